// Round 1
// baseline (145.555 us; speedup 1.0000x reference)
//
#include <hip/hip_runtime.h>
#include <math.h>

#pragma clang fp contract(off)

#define IMRES 128
#define MESH 20
#define NVERT (MESH*MESH)
#define NCELL ((MESH-1)*(MESH-1))
#define NTRI (2*NCELL)
#define RGBRES 128
#define BCGRES 384
#define BATCH 2
#define TRI_STRIDE 12
#define BIGF 1000000000.0f

__device__ __forceinline__ void mm3(const float* A, const float* B, float* C){
#pragma unroll
  for (int i=0;i<3;++i)
#pragma unroll
    for (int j=0;j<3;++j)
      C[i*3+j] = A[i*3+0]*B[0*3+j] + A[i*3+1]*B[1*3+j] + A[i*3+2]*B[2*3+j];
}

// Separable gaussian blur, one axis per launch. axis==0: along H, axis==1: along W.
__global__ void blur_pass(const float* __restrict__ in, float* __restrict__ out, int axis){
  int idx = blockIdx.x*blockDim.x + threadIdx.x;
  if (idx >= IMRES*IMRES*3) return;
  int c = idx % 3;
  int j = (idx/3) % IMRES;
  int i = idx/(3*IMRES);
  float kw[13]; float s = 0.0f;
#pragma unroll
  for (int t=0;t<13;++t){
    float x = (float)(t-6)/2.0f;
    float w = expf(-0.5f*(x*x));
    kw[t] = w; s += w;
  }
#pragma unroll
  for (int t=0;t<13;++t) kw[t] = kw[t]/s;
  float acc = 0.0f;
#pragma unroll
  for (int t=0;t<13;++t){
    int p = ((axis==0)? i : j) - 6 + t;
    p = min(max(p,0), IMRES-1);
    int src = (axis==0) ? ((p*IMRES + j)*3 + c) : ((i*IMRES + p)*3 + c);
    acc = acc + kw[t]*in[src];
  }
  out[idx] = acc;
}

// One block: sample 400 verts from blurred xyz, rotate+project per batch,
// emit per-(batch,tri) raster records.
__global__ void setup_kernel(const float* __restrict__ blurred,
                             const float* __restrict__ angles,
                             float* __restrict__ tri){
  __shared__ float vnd[BATCH*NVERT*3]; // ndcx, ndcy, z
  const int tid = threadIdx.x;
  const float PI_F = 3.14159274101257324f;   // float32(np.pi)
  const float F    = 11.4300523027613427f;   // 1/tan(5 deg)
  const float DIST = 5.7150261513806713f;    // 0.5/tan(5 deg)
  if (tid < NVERT){
    int vi = tid / MESH, vj = tid % MESH;
    float u  = (float)((double)vj/19.0);     // vertuv computed in f64, cast f32
    float vv = (float)((double)vi/19.0);
    float x = u*127.0f, y = vv*127.0f;
    int x0 = (int)fminf(fmaxf(floorf(x),0.0f),126.0f);
    int y0 = (int)fminf(fmaxf(floorf(y),0.0f),126.0f);
    float fx = x-(float)x0, fy = y-(float)y0;
    float p[3];
#pragma unroll
    for (int ch=0; ch<3; ++ch){
      float t00=blurred[(y0*IMRES+x0)*3+ch];
      float t01=blurred[(y0*IMRES+x0+1)*3+ch];
      float t10=blurred[((y0+1)*IMRES+x0)*3+ch];
      float t11=blurred[((y0+1)*IMRES+x0+1)*3+ch];
      p[ch] = (t00*(1.0f-fx)+t01*fx)*(1.0f-fy) + (t10*(1.0f-fx)+t11*fx)*fy;
    }
    float lo0 = (-60.0f*PI_F)/180.0f, hi0 = (60.0f*PI_F)/180.0f;
    float lo1 = (-90.0f*PI_F)/180.0f, hi1 = (90.0f*PI_F)/180.0f;
    for (int b=0;b<BATCH;++b){
      float ax = angles[b*3+0]*(hi0-lo0)+lo0;
      float ay = angles[b*3+1]*(hi1-lo1)+lo1;
      float az = 0.0f; // angle-z range is [0,0]
      float cx=cosf(ax), sx=sinf(ax);
      float cy=cosf(ay), sy=sinf(ay);
      float cz=cosf(az), sz=sinf(az);
      float Rx[9]={1.f,0.f,0.f,  0.f,cx,-sx,  0.f,sx,cx};
      float Ry[9]={cy,0.f,sy,    0.f,1.f,0.f, -sy,0.f,cy};
      float Rz[9]={cz,-sz,0.f,   sz,cz,0.f,   0.f,0.f,1.f};
      float M1[9], R[9];
      mm3(Rz,Ry,M1); mm3(M1,Rx,R);
      float X0 = R[0]*p[0]+R[1]*p[1]+R[2]*p[2];
      float X1 = R[3]*p[0]+R[4]*p[1]+R[5]*p[2];
      float X2 = R[6]*p[0]+R[7]*p[1]+R[8]*p[2] + DIST;
      vnd[(b*NVERT+tid)*3+0] = (F*X0)/X2;
      vnd[(b*NVERT+tid)*3+1] = (F*X1)/X2;
      vnd[(b*NVERT+tid)*3+2] = X2;
    }
  }
  __syncthreads();
  for (int job=tid; job<BATCH*NTRI; job+=blockDim.x){
    int b = job / NTRI, t = job % NTRI;
    int i0,i1,i2;
    if (t < NCELL){ int r=t/19, cc=t%19; i0=r*MESH+cc; i1=(r+1)*MESH+cc; i2=r*MESH+cc+1; }
    else { int tt=t-NCELL; int r=tt/19, cc=tt%19; i0=(r+1)*MESH+cc; i1=(r+1)*MESH+cc+1; i2=r*MESH+cc+1; }
    const float* V0=&vnd[(b*NVERT+i0)*3];
    const float* V1=&vnd[(b*NVERT+i1)*3];
    const float* V2=&vnd[(b*NVERT+i2)*3];
    float area = (V1[0]-V0[0])*(V2[1]-V0[1]) - (V1[1]-V0[1])*(V2[0]-V0[0]);
    int valid = (fabsf(area) > 1e-6f) ? 1 : 0;
    float as = valid ? area : 1.0f;
    float* T = &tri[(b*NTRI+t)*TRI_STRIDE];
    T[0]=V0[0]; T[1]=V0[1]; T[2]=V1[0]; T[3]=V1[1]; T[4]=V2[0]; T[5]=V2[1];
    T[6]=V0[2]; T[7]=V1[2]; T[8]=V2[2]; T[9]=as; T[10]=(float)valid; T[11]=0.0f;
  }
}

__global__ __launch_bounds__(256)
void raster_kernel(const float* __restrict__ tri,
                   const float* __restrict__ angles,
                   const float* __restrict__ rgb,
                   const float* __restrict__ bcg,
                   float* __restrict__ out){
  __shared__ float lt[NTRI*TRI_STRIDE]; // 34656 B
  const int b = blockIdx.y;
  const float* tb = tri + b*NTRI*TRI_STRIDE;
  for (int k=threadIdx.x; k<NTRI*TRI_STRIDE; k+=256) lt[k]=tb[k];
  __syncthreads();
  int pid = blockIdx.x*256 + threadIdx.x; // 0..16383
  int i = pid>>7, j = pid&127;
  float px = (((float)j+0.5f)/128.0f)*2.0f - 1.0f; // exact (pow2)
  float py = (((float)i+0.5f)/128.0f)*2.0f - 1.0f;

  float bestd = BIGF; int best = 0;
  for (int t=0;t<NTRI;++t){
    const float* T=&lt[t*TRI_STRIDE];
    float v0x=T[0],v0y=T[1],v1x=T[2],v1y=T[3],v2x=T[4],v2y=T[5];
    float z0=T[6],z1=T[7],z2=T[8],as=T[9];
    bool valid = (T[10]!=0.0f);
    float w0 = ((v2x-v1x)*(py-v1y) - (v2y-v1y)*(px-v1x))/as;
    float w1 = ((v0x-v2x)*(py-v2y) - (v0y-v2y)*(px-v2x))/as;
    float w2 = 1.0f-w0-w1;
    bool inside = (w0>=0.0f)&&(w1>=0.0f)&&(w2>=0.0f)&&valid;
    float d = inside ? ((w0*z0+w1*z1)+w2*z2) : BIGF;
    if (d < bestd){ bestd=d; best=t; } // strict < == argmin first-occurrence
  }
  bool mask = bestd < BIGF;

  // recompute barycentrics of the winning triangle
  const float* T=&lt[best*TRI_STRIDE];
  float as=T[9];
  float w0 = ((T[4]-T[2])*(py-T[3]) - (T[5]-T[3])*(px-T[2]))/as;
  float w1 = ((T[0]-T[4])*(py-T[5]) - (T[1]-T[5])*(px-T[4]))/as;
  float w2 = 1.0f-w0-w1;

  int t=best, i0,i1,i2;
  if (t<NCELL){ int r=t/19, cc=t%19; i0=r*MESH+cc; i1=(r+1)*MESH+cc; i2=r*MESH+cc+1; }
  else { int tt=t-NCELL; int r=tt/19, cc=tt%19; i0=(r+1)*MESH+cc; i1=(r+1)*MESH+cc+1; i2=r*MESH+cc+1; }
  float u0=(float)((double)(i0%MESH)/19.0), q0=(float)((double)(i0/MESH)/19.0);
  float u1=(float)((double)(i1%MESH)/19.0), q1=(float)((double)(i1/MESH)/19.0);
  float u2=(float)((double)(i2%MESH)/19.0), q2=(float)((double)(i2/MESH)/19.0);
  float uu_ = (w0*u0+w1*u1)+w2*u2;
  float vv_ = (w0*q0+w1*q1)+w2*q2;
  uu_ = fminf(fmaxf(uu_,0.0f),1.0f);
  vv_ = fminf(fmaxf(vv_,0.0f),1.0f);

  float col[3];
  {
    float x = uu_*127.0f, y = vv_*127.0f;
    int x0=(int)fminf(fmaxf(floorf(x),0.0f),126.0f);
    int y0=(int)fminf(fmaxf(floorf(y),0.0f),126.0f);
    float fx=x-(float)x0, fy=y-(float)y0;
#pragma unroll
    for(int ch=0;ch<3;++ch){
      float t00=rgb[(y0*RGBRES+x0)*3+ch];
      float t01=rgb[(y0*RGBRES+x0+1)*3+ch];
      float t10=rgb[((y0+1)*RGBRES+x0)*3+ch];
      float t11=rgb[((y0+1)*RGBRES+x0+1)*3+ch];
      col[ch]=(t00*(1.0f-fx)+t01*fx)*(1.0f-fy)+(t10*(1.0f-fx)+t11*fx)*fy;
    }
  }
  float minb = fminf(fminf(w0,w1),w2);
  float alpha = mask ? (1.0f/(1.0f+expf(-(minb/0.05f)))) : 0.0f;

  const float RH   = (float)(128.0/384.0);
  const float OMRH = (float)(1.0-128.0/384.0);
  float y1 = OMRH*angles[b*3+0];
  float x1 = OMRH*angles[b*3+1];
  float tu = (float)j/127.0f, tv = (float)i/127.0f;
  float bu = fminf(fmaxf(x1 + RH*tu,0.0f),1.0f);
  float bv = fminf(fmaxf(y1 + RH*tv,0.0f),1.0f);
  float bg[3];
  {
    float x=bu*383.0f, y=bv*383.0f;
    int x0=(int)fminf(fmaxf(floorf(x),0.0f),382.0f);
    int y0=(int)fminf(fmaxf(floorf(y),0.0f),382.0f);
    float fx=x-(float)x0, fy=y-(float)y0;
#pragma unroll
    for(int ch=0;ch<3;++ch){
      float t00=bcg[(y0*BCGRES+x0)*3+ch];
      float t01=bcg[(y0*BCGRES+x0+1)*3+ch];
      float t10=bcg[((y0+1)*BCGRES+x0)*3+ch];
      float t11=bcg[((y0+1)*BCGRES+x0+1)*3+ch];
      bg[ch]=(t00*(1.0f-fx)+t01*fx)*(1.0f-fy)+(t10*(1.0f-fx)+t11*fx)*fy;
    }
  }
  float* o = &out[((b*IMRES+i)*IMRES+j)*3];
#pragma unroll
  for(int ch=0;ch<3;++ch) o[ch] = alpha*col[ch] + (1.0f-alpha)*bg[ch];
}

extern "C" void kernel_launch(void* const* d_in, const int* in_sizes, int n_in,
                              void* d_out, int out_size, void* d_ws, size_t ws_size,
                              hipStream_t stream) {
  const float* angles = (const float*)d_in[0];
  const float* xyz    = (const float*)d_in[1];
  const float* rgb    = (const float*)d_in[2];
  const float* bcg    = (const float*)d_in[3];
  float* out = (float*)d_out;
  float* ws  = (float*)d_ws;
  float* tmp     = ws;               // 49152 f32
  float* blurred = ws + 49152;       // 49152 f32
  float* tri     = ws + 98304;       // 2*722*12 = 17328 f32
  const int n = IMRES*IMRES*3;
  blur_pass<<<(n+255)/256, 256, 0, stream>>>(xyz, tmp, 0);
  blur_pass<<<(n+255)/256, 256, 0, stream>>>(tmp, blurred, 1);
  setup_kernel<<<1, 512, 0, stream>>>(blurred, angles, tri);
  dim3 g(64, BATCH);
  raster_kernel<<<g, 256, 0, stream>>>(tri, angles, rgb, bcg, out);
}

// Round 2
// 45.846 us; speedup vs baseline: 3.1749x; 3.1749x over previous
//
#include <hip/hip_runtime.h>
#include <math.h>

#pragma clang fp contract(off)

#define IMRES 128
#define MESH 20
#define NVERT (MESH*MESH)
#define NCELL ((MESH-1)*(MESH-1))
#define NTRI (2*NCELL)
#define RGBRES 128
#define BCGRES 384
#define BATCH 2
#define TRI_F 12
#define CHUNKS 4
#define CH_TRI 181   // ceil(722/4)
#define BIGF 1000000000.0f

__device__ __forceinline__ void mm3(const float* A, const float* B, float* C){
#pragma unroll
  for (int i=0;i<3;++i)
#pragma unroll
    for (int j=0;j<3;++j)
      C[i*3+j] = A[i*3+0]*B[0*3+j] + A[i*3+1]*B[1*3+j] + A[i*3+2]*B[2*3+j];
}

// Separable gaussian blur, one axis per launch. axis==0: along H, axis==1: along W.
__global__ void blur_pass(const float* __restrict__ in, float* __restrict__ out, int axis){
  int idx = blockIdx.x*blockDim.x + threadIdx.x;
  if (idx >= IMRES*IMRES*3) return;
  int c = idx % 3;
  int j = (idx/3) % IMRES;
  int i = idx/(3*IMRES);
  float kw[13]; float s = 0.0f;
#pragma unroll
  for (int t=0;t<13;++t){
    float x = (float)(t-6)/2.0f;
    float w = expf(-0.5f*(x*x));
    kw[t] = w; s += w;
  }
#pragma unroll
  for (int t=0;t<13;++t) kw[t] = kw[t]/s;
  float acc = 0.0f;
#pragma unroll
  for (int t=0;t<13;++t){
    int p = ((axis==0)? i : j) - 6 + t;
    p = min(max(p,0), IMRES-1);
    int src = (axis==0) ? ((p*IMRES + j)*3 + c) : ((i*IMRES + p)*3 + c);
    acc = acc + kw[t]*in[src];
  }
  out[idx] = acc;
}

// One block: sample 400 verts from blurred xyz, rotate+project per batch,
// emit per-(batch,tri) raster records:
// [v1x,v1y,d21x,d21y, v2x,v2y,d02x,d02y, dA,dB,dC, inv_as]
__global__ void setup_kernel(const float* __restrict__ blurred,
                             const float* __restrict__ angles,
                             float* __restrict__ tri){
  __shared__ float vnd[BATCH*NVERT*3]; // ndcx, ndcy, z
  const int tid = threadIdx.x;
  const float PI_F = 3.14159274101257324f;   // float32(np.pi)
  const float F    = 11.4300523027613427f;   // 1/tan(5 deg)
  const float DIST = 5.7150261513806713f;    // 0.5/tan(5 deg)
  if (tid < NVERT){
    int vi = tid / MESH, vj = tid % MESH;
    float u  = (float)((double)vj/19.0);     // vertuv computed in f64, cast f32
    float vv = (float)((double)vi/19.0);
    float x = u*127.0f, y = vv*127.0f;
    int x0 = (int)fminf(fmaxf(floorf(x),0.0f),126.0f);
    int y0 = (int)fminf(fmaxf(floorf(y),0.0f),126.0f);
    float fx = x-(float)x0, fy = y-(float)y0;
    float p[3];
#pragma unroll
    for (int ch=0; ch<3; ++ch){
      float t00=blurred[(y0*IMRES+x0)*3+ch];
      float t01=blurred[(y0*IMRES+x0+1)*3+ch];
      float t10=blurred[((y0+1)*IMRES+x0)*3+ch];
      float t11=blurred[((y0+1)*IMRES+x0+1)*3+ch];
      p[ch] = (t00*(1.0f-fx)+t01*fx)*(1.0f-fy) + (t10*(1.0f-fx)+t11*fx)*fy;
    }
    float lo0 = (-60.0f*PI_F)/180.0f, hi0 = (60.0f*PI_F)/180.0f;
    float lo1 = (-90.0f*PI_F)/180.0f, hi1 = (90.0f*PI_F)/180.0f;
    for (int b=0;b<BATCH;++b){
      float ax = angles[b*3+0]*(hi0-lo0)+lo0;
      float ay = angles[b*3+1]*(hi1-lo1)+lo1;
      float az = 0.0f; // angle-z range is [0,0]
      float cx=cosf(ax), sx=sinf(ax);
      float cy=cosf(ay), sy=sinf(ay);
      float cz=cosf(az), sz=sinf(az);
      float Rx[9]={1.f,0.f,0.f,  0.f,cx,-sx,  0.f,sx,cx};
      float Ry[9]={cy,0.f,sy,    0.f,1.f,0.f, -sy,0.f,cy};
      float Rz[9]={cz,-sz,0.f,   sz,cz,0.f,   0.f,0.f,1.f};
      float M1[9], R[9];
      mm3(Rz,Ry,M1); mm3(M1,Rx,R);
      float X0 = R[0]*p[0]+R[1]*p[1]+R[2]*p[2];
      float X1 = R[3]*p[0]+R[4]*p[1]+R[5]*p[2];
      float X2 = R[6]*p[0]+R[7]*p[1]+R[8]*p[2] + DIST;
      vnd[(b*NVERT+tid)*3+0] = (F*X0)/X2;
      vnd[(b*NVERT+tid)*3+1] = (F*X1)/X2;
      vnd[(b*NVERT+tid)*3+2] = X2;
    }
  }
  __syncthreads();
  for (int job=tid; job<BATCH*NTRI; job+=blockDim.x){
    int b = job / NTRI, t = job % NTRI;
    int i0,i1,i2;
    if (t < NCELL){ int r=t/19, cc=t%19; i0=r*MESH+cc; i1=(r+1)*MESH+cc; i2=r*MESH+cc+1; }
    else { int tt=t-NCELL; int r=tt/19, cc=tt%19; i0=(r+1)*MESH+cc; i1=(r+1)*MESH+cc+1; i2=r*MESH+cc+1; }
    const float* V0=&vnd[(b*NVERT+i0)*3];
    const float* V1=&vnd[(b*NVERT+i1)*3];
    const float* V2=&vnd[(b*NVERT+i2)*3];
    float v0x=V0[0], v0y=V0[1], z0=V0[2];
    float v1x=V1[0], v1y=V1[1], z1=V1[2];
    float v2x=V2[0], v2y=V2[1], z2=V2[2];
    // area exactly as reference
    float area = (v1x-v0x)*(v2y-v0y) - (v1y-v0y)*(v2x-v0x);
    bool valid = (fabsf(area) > 1e-6f);
    float as = valid ? area : 1.0f;
    float inv = 1.0f/as;               // correctly-rounded IEEE divide
    float d21x = v2x-v1x, d21y = v2y-v1y;  // same fl() as reference's inline subs
    float d02x = v0x-v2x, d02y = v0y-v2y;
    // depth plane: depth = z2 + (e0*(z0-z2) + e1*(z1-z2))*inv
    float dz0 = z0-z2, dz1 = z1-z2;
    float dA = (-d21y*dz0 - d02y*dz1)*inv;
    float dB = ( d21x*dz0 + d02x*dz1)*inv;
    float C0 = d21y*v1x - d21x*v1y;
    float C1 = d02y*v2x - d02x*v2y;
    float dC = z2 + (C0*dz0 + C1*dz1)*inv;
    if (!valid){ dA=0.0f; dB=0.0f; dC=BIGF; inv=__uint_as_float(0x7fc00000u); } // NaN -> inside always false
    float* T = &tri[(b*NTRI+t)*TRI_F];
    T[0]=v1x; T[1]=v1y; T[2]=d21x; T[3]=d21y;
    T[4]=v2x; T[5]=v2y; T[6]=d02x; T[7]=d02y;
    T[8]=dA;  T[9]=dB;  T[10]=dC;  T[11]=inv;
  }
}

// 64 pixels per block, 4 waves, each wave covers a 181-triangle chunk; LDS argmin reduce.
__global__ __launch_bounds__(256)
void raster_kernel(const float* __restrict__ tri,
                   const float* __restrict__ angles,
                   const float* __restrict__ rgb,
                   const float* __restrict__ bcg,
                   float* __restrict__ out){
  __shared__ float4 lt4[NTRI*3];     // 722 records x 48B = 34656B
  __shared__ float sdep[256];
  __shared__ int   sidx[256];
  float* lt = (float*)lt4;
  const int b = blockIdx.y;
  const float* tb = tri + b*NTRI*TRI_F;
  {
    const float4* src = (const float4*)tb;
    for (int k=threadIdx.x; k<NTRI*3; k+=256) lt4[k]=src[k];
  }
  __syncthreads();
  const int lane  = threadIdx.x & 63;
  const int chunk = threadIdx.x >> 6;
  const int pix = blockIdx.x*64 + lane;
  const int i = pix>>7, j = pix&127;
  const float px = (((float)j+0.5f)/128.0f)*2.0f - 1.0f; // exact (pow2)
  const float py = (((float)i+0.5f)/128.0f)*2.0f - 1.0f;

  float bestd = BIGF; int bestt = 0;
  const int t0 = chunk*CH_TRI;
  const int t1 = (t0+CH_TRI < NTRI) ? t0+CH_TRI : NTRI;
  for (int t=t0; t<t1; ++t){
    float4 q0 = lt4[t*3+0];
    float4 q1 = lt4[t*3+1];
    float4 q2 = lt4[t*3+2];
    float e0 = q0.z*(py-q0.y) - q0.w*(px-q0.x);
    float e1 = q1.z*(py-q1.y) - q1.w*(px-q1.x);
    float w0 = e0*q2.w, w1 = e1*q2.w;
    float w2 = 1.0f - w0 - w1;
    bool inside = (w0>=0.0f) && (w1>=0.0f) && (w2>=0.0f); // NaN -> false
    float d = q2.x*px + q2.y*py + q2.z;
    d = inside ? d : BIGF;
    if (d < bestd){ bestd=d; bestt=t; }  // strict < == first occurrence in chunk
  }
  sdep[threadIdx.x] = bestd; sidx[threadIdx.x] = bestt;
  __syncthreads();
  if (threadIdx.x >= 64) return;
#pragma unroll
  for (int c=1;c<CHUNKS;++c){
    float d = sdep[c*64+lane]; int t = sidx[c*64+lane];
    if (d < bestd || (d == bestd && t < bestt)) { bestd=d; bestt=t; }
  }
  bool mask = bestd < BIGF;

  // recompute barycentrics of the winning triangle (same exprs as main loop)
  const float* T = &lt[bestt*TRI_F];
  float e0 = T[2]*(py-T[1]) - T[3]*(px-T[0]);
  float e1 = T[6]*(py-T[5]) - T[7]*(px-T[4]);
  float w0 = e0*T[11], w1 = e1*T[11];
  float w2 = 1.0f - w0 - w1;

  int t=bestt, i0,i1,i2;
  if (t<NCELL){ int r=t/19, cc=t%19; i0=r*MESH+cc; i1=(r+1)*MESH+cc; i2=r*MESH+cc+1; }
  else { int tt=t-NCELL; int r=tt/19, cc=tt%19; i0=(r+1)*MESH+cc; i1=(r+1)*MESH+cc+1; i2=r*MESH+cc+1; }
  float u0=(float)((double)(i0%MESH)/19.0), q0=(float)((double)(i0/MESH)/19.0);
  float u1=(float)((double)(i1%MESH)/19.0), q1=(float)((double)(i1/MESH)/19.0);
  float u2=(float)((double)(i2%MESH)/19.0), q2=(float)((double)(i2/MESH)/19.0);
  float uu_ = (w0*u0+w1*u1)+w2*u2;
  float vv_ = (w0*q0+w1*q1)+w2*q2;
  uu_ = fminf(fmaxf(uu_,0.0f),1.0f);   // fmaxf/fminf sanitize NaN -> finite
  vv_ = fminf(fmaxf(vv_,0.0f),1.0f);

  float col[3];
  {
    float x = uu_*127.0f, y = vv_*127.0f;
    int x0=(int)fminf(fmaxf(floorf(x),0.0f),126.0f);
    int y0=(int)fminf(fmaxf(floorf(y),0.0f),126.0f);
    float fx=x-(float)x0, fy=y-(float)y0;
#pragma unroll
    for(int ch=0;ch<3;++ch){
      float t00=rgb[(y0*RGBRES+x0)*3+ch];
      float t01=rgb[(y0*RGBRES+x0+1)*3+ch];
      float t10=rgb[((y0+1)*RGBRES+x0)*3+ch];
      float t11=rgb[((y0+1)*RGBRES+x0+1)*3+ch];
      col[ch]=(t00*(1.0f-fx)+t01*fx)*(1.0f-fy)+(t10*(1.0f-fx)+t11*fx)*fy;
    }
  }
  float minb = fminf(fminf(w0,w1),w2);
  float alpha = mask ? (1.0f/(1.0f+expf(-(minb/0.05f)))) : 0.0f;

  const float RH   = (float)(128.0/384.0);
  const float OMRH = (float)(1.0-128.0/384.0);
  float y1 = OMRH*angles[b*3+0];
  float x1 = OMRH*angles[b*3+1];
  float tu = (float)j/127.0f, tv = (float)i/127.0f;
  float bu = fminf(fmaxf(x1 + RH*tu,0.0f),1.0f);
  float bv = fminf(fmaxf(y1 + RH*tv,0.0f),1.0f);
  float bg[3];
  {
    float x=bu*383.0f, y=bv*383.0f;
    int x0=(int)fminf(fmaxf(floorf(x),0.0f),382.0f);
    int y0=(int)fminf(fmaxf(floorf(y),0.0f),382.0f);
    float fx=x-(float)x0, fy=y-(float)y0;
#pragma unroll
    for(int ch=0;ch<3;++ch){
      float t00=bcg[(y0*BCGRES+x0)*3+ch];
      float t01=bcg[(y0*BCGRES+x0+1)*3+ch];
      float t10=bcg[((y0+1)*BCGRES+x0)*3+ch];
      float t11=bcg[((y0+1)*BCGRES+x0+1)*3+ch];
      bg[ch]=(t00*(1.0f-fx)+t01*fx)*(1.0f-fy)+(t10*(1.0f-fx)+t11*fx)*fy;
    }
  }
  float* o = &out[((b*IMRES+i)*IMRES+j)*3];
#pragma unroll
  for(int ch=0;ch<3;++ch) o[ch] = alpha*col[ch] + (1.0f-alpha)*bg[ch];
}

extern "C" void kernel_launch(void* const* d_in, const int* in_sizes, int n_in,
                              void* d_out, int out_size, void* d_ws, size_t ws_size,
                              hipStream_t stream) {
  const float* angles = (const float*)d_in[0];
  const float* xyz    = (const float*)d_in[1];
  const float* rgb    = (const float*)d_in[2];
  const float* bcg    = (const float*)d_in[3];
  float* out = (float*)d_out;
  float* ws  = (float*)d_ws;
  float* tmp     = ws;               // 49152 f32
  float* blurred = ws + 49152;       // 49152 f32
  float* tri     = ws + 98304;       // 2*722*12 = 17328 f32
  const int n = IMRES*IMRES*3;
  blur_pass<<<(n+255)/256, 256, 0, stream>>>(xyz, tmp, 0);
  blur_pass<<<(n+255)/256, 256, 0, stream>>>(tmp, blurred, 1);
  setup_kernel<<<1, 512, 0, stream>>>(blurred, angles, tri);
  dim3 g(256, BATCH);
  raster_kernel<<<g, 256, 0, stream>>>(tri, angles, rgb, bcg, out);
}